// Round 2
// baseline (600.528 us; speedup 1.0000x reference)
//
#include <hip/hip_runtime.h>

// ChemResBlock: A=2048 atoms, D=64 depth, F=12 taps.
// out[a,o] = sum_{n,f} conn[a][n*12+f] * Gt[o][n*12+f] + bterm[a,o]
// conn viewed as (2048 x 24576) row-major is contiguous in exactly this K order.
// R2: conn pre-converted to bf16 once; GEMM is barrier-free 32x32x16 MFMA with
// per-lane 16B fragment loads straight from global (no LDS staging).

#define A_N 2048
#define D_N 64
#define F_N 12
#define K_TOTAL (A_N * F_N)        // 24576
#define NSPLIT 32
#define KSEG (K_TOTAL / NSPLIT)    // 768
#define KSTEPS (KSEG / 16)         // 48

typedef short short8 __attribute__((ext_vector_type(8)));
typedef float f32x16 __attribute__((ext_vector_type(16)));

// pack two floats to bf16 pair with round-to-nearest-even
__device__ __forceinline__ unsigned pk_bf16(float a, float b) {
  unsigned ua = __float_as_uint(a);
  unsigned ub = __float_as_uint(b);
  ua += 0x7fffu + ((ua >> 16) & 1u);
  ub += 0x7fffu + ((ub >> 16) & 1u);
  return (ua >> 16) | (ub & 0xffff0000u);
}

// ---------------- one-time: conn fp32 -> bf16 (streaming) ----------------
__global__ void k_conv(const float* __restrict__ conn, uint4* __restrict__ connb) {
  // 50,331,648 floats, 8 per thread
  size_t i = (size_t)blockIdx.x * 256 + threadIdx.x;  // 0 .. 6291455
  const float4* src = (const float4*)conn + i * 2;
  float4 c0 = src[0];
  float4 c1 = src[1];
  uint4 o;
  o.x = pk_bf16(c0.x, c0.y);
  o.y = pk_bf16(c0.z, c0.w);
  o.z = pk_bf16(c1.x, c1.y);
  o.w = pk_bf16(c1.z, c1.w);
  connb[i] = o;
}

// ---------------- prep: x (2048x64) -> xt (64x2048) ----------------
__global__ void k_transpose_x(const float* __restrict__ x, float* __restrict__ xt) {
  __shared__ float ld[64][65];
  int m0 = blockIdx.x * 64;
  int t = threadIdx.x;
  int r = t >> 2, cq = (t & 3) * 16;
  const float4* src = (const float4*)(x + (size_t)(m0 + r) * 64 + cq);
#pragma unroll
  for (int i = 0; i < 4; ++i) {
    float4 v = src[i];
    ld[r][cq + i * 4 + 0] = v.x;
    ld[r][cq + i * 4 + 1] = v.y;
    ld[r][cq + i * 4 + 2] = v.z;
    ld[r][cq + i * 4 + 3] = v.w;
  }
  __syncthreads();
  int c = t >> 2, ml0 = (t & 3) * 16;
  float4* dst = (float4*)(xt + (size_t)c * 2048 + m0 + ml0);
#pragma unroll
  for (int i = 0; i < 4; ++i) {
    float4 v;
    v.x = ld[ml0 + i * 4 + 0][c];
    v.y = ld[ml0 + i * 4 + 1][c];
    v.z = ld[ml0 + i * 4 + 2][c];
    v.w = ld[ml0 + i * 4 + 3][c];
    dst[i] = v;
  }
}

// ---------------- prep: bterm_t[o][a] for both filter sets ----------------
__global__ void k_bterm(const float* __restrict__ bond, const float* __restrict__ f0,
                        const float* __restrict__ f1, float* __restrict__ bt0,
                        float* __restrict__ bt1) {
  int a = blockIdx.x * 64 + (threadIdx.x & 63);
  int o = blockIdx.y * 4 + (threadIdx.x >> 6);
  float s0 = 0.f, s1 = 0.f;
#pragma unroll
  for (int f = 0; f < F_N; ++f) {
#pragma unroll
    for (int j = 0; j < 2; ++j) {
      float bv = bond[a * 24 + f * 2 + j];
      s0 += bv * f0[o * 792 + f * 66 + 64 + j];
      s1 += bv * f1[o * 792 + f * 66 + 64 + j];
    }
  }
  bt0[o * 2048 + a] = s0;
  bt1[o * 2048 + a] = s1;
}

// ---------------- per-layer: Gt[o][n*12+f] = sum_d vt[d][n]*filt[o][f][d] ----------------
__global__ void k_g(const float* __restrict__ vt, const float* __restrict__ filt,
                    unsigned* __restrict__ gt /* bf16 pairs */) {
  __shared__ float W[12][64];
  int o = blockIdx.y;
  int t = threadIdx.x;
  for (int i = t; i < 768; i += 256) W[i >> 6][i & 63] = filt[o * 792 + (i >> 6) * 66 + (i & 63)];
  __syncthreads();
  int n = blockIdx.x * 256 + t;
  float acc[12] = {0.f, 0.f, 0.f, 0.f, 0.f, 0.f, 0.f, 0.f, 0.f, 0.f, 0.f, 0.f};
#pragma unroll 4
  for (int d = 0; d < 64; ++d) {
    float v = vt[d * 2048 + n];
#pragma unroll
    for (int f = 0; f < F_N; ++f) acc[f] += v * W[f][d];
  }
  unsigned* dst = gt + ((size_t)o * K_TOTAL + n * 12) / 2;
#pragma unroll
  for (int i = 0; i < 6; ++i) dst[i] = pk_bf16(acc[2 * i], acc[2 * i + 1]);
}

// ---------------- per-layer: barrier-free split-K GEMM ----------------
// Wave computes a 32(o) x 32(atom) tile over K-chunk 768.
// A = gt[o][k]   : lane holds A[m=lane&31][k = 8*(lane>>5) + j], 16B contiguous
// B = conn[a][k] : lane holds B[n=lane&31][k = 8*(lane>>5) + j], 16B contiguous
// D: col(atom) = lane&31, row(o) = (reg&3) + 8*(reg>>2) + 4*(lane>>5)
__launch_bounds__(256)
__global__ void k_big(const unsigned short* __restrict__ connb,
                      const unsigned short* __restrict__ gt, float* __restrict__ part) {
  int t = threadIdx.x, lane = t & 63;
  int w = blockIdx.x * 4 + (t >> 6);  // 0..4095
  int mt = w >> 6;                    // 0..63  (atom tile, 32 rows)
  int r = w & 63;
  int ks = r >> 1;                    // 0..31
  int ot = r & 1;                     // o tile
  int m0 = mt * 32, o0 = ot * 32, k0 = ks * KSEG;

  const short8* ap = (const short8*)(gt + (size_t)(o0 + (lane & 31)) * K_TOTAL + k0 + ((lane >> 5) << 3));
  const short8* bp = (const short8*)(connb + (size_t)(m0 + (lane & 31)) * K_TOTAL + k0 + ((lane >> 5) << 3));

  f32x16 acc;
#pragma unroll
  for (int i = 0; i < 16; ++i) acc[i] = 0.f;

#pragma unroll 4
  for (int k = 0; k < KSTEPS; ++k) {
    short8 a = ap[0];
    short8 b = bp[0];
    acc = __builtin_amdgcn_mfma_f32_32x32x16_bf16(a, b, acc, 0, 0, 0);
    ap += 2;  // 16 bf16 elems
    bp += 2;
  }

  float* pp = part + (size_t)ks * (64 * 2048);
  int m = m0 + (lane & 31);
  int rbase = o0 + 4 * (lane >> 5);
#pragma unroll
  for (int rg = 0; rg < 16; ++rg) {
    int o = rbase + (rg & 3) + 8 * (rg >> 2);
    pp[o * 2048 + m] = acc[rg];
  }
}

// ---------------- per-layer epilogue: sum partials + bterm (+x) + relu ----------------
__global__ void k_reduce(const float* __restrict__ part, const float* __restrict__ bt,
                         const float* __restrict__ xt, float* __restrict__ curt,
                         float* __restrict__ outp, int residual, int final_layer) {
  int idx = blockIdx.x * 256 + threadIdx.x;  // 0 .. 64*2048-1, layout [o][m]
  float s = bt[idx];
#pragma unroll
  for (int sI = 0; sI < NSPLIT; ++sI) s += part[(size_t)sI * (64 * 2048) + idx];
  if (residual) s += xt[idx];
  s = fmaxf(s, 0.f);
  curt[idx] = s;
  if (final_layer) {
    int o = idx >> 11, m = idx & 2047;
    outp[m * 64 + o] = s;
  }
}

extern "C" void kernel_launch(void* const* d_in, const int* in_sizes, int n_in,
                              void* d_out, int out_size, void* d_ws, size_t ws_size,
                              hipStream_t stream) {
  const float* x    = (const float*)d_in[0];  // (2048, 64)
  const float* conn = (const float*)d_in[1];  // (2048, 2048, 12)
  const float* bond = (const float*)d_in[2];  // (2048, 12, 2)
  const float* f0   = (const float*)d_in[3];  // (64, 12, 66)
  const float* f1   = (const float*)d_in[4];
  float* out = (float*)d_out;                 // (2048, 64)

  char* ws = (char*)d_ws;
  float* xt   = (float*)(ws + 0);              // 64x2048 fp32            512 KB
  float* curt = (float*)(ws + 524288);         // 64x2048 fp32            512 KB
  float* bt0  = (float*)(ws + 1048576);        // 64x2048 fp32            512 KB
  float* bt1  = (float*)(ws + 1572864);        // 64x2048 fp32            512 KB
  unsigned short* gt = (unsigned short*)(ws + 2097152);   // 64x24576 bf16  3 MB
  float* part = (float*)(ws + 5242880);        // 32 x 64x2048 fp32       16 MB
  unsigned short* connb = (unsigned short*)(ws + 33554432);  // 2048x24576 bf16  96 MB
  // total ~130 MB of d_ws used

  k_conv<<<24576, 256, 0, stream>>>(conn, (uint4*)connb);
  k_transpose_x<<<32, 256, 0, stream>>>(x, xt);
  k_bterm<<<dim3(32, 16), 256, 0, stream>>>(bond, f0, f1, bt0, bt1);

  for (int layer = 0; layer < 4; ++layer) {
    const float* filt = (layer < 2) ? f0 : f1;
    const float* bt   = (layer < 2) ? bt0 : bt1;
    const float* vin  = (layer == 0) ? xt : curt;
    k_g<<<dim3(8, 64), 256, 0, stream>>>(vin, filt, (unsigned*)gt);
    k_big<<<1024, 256, 0, stream>>>(connb, gt, part);
    k_reduce<<<512, 256, 0, stream>>>(part, bt, xt, curt, out, layer & 1, layer == 3);
  }
}

// Round 3
// 493.581 us; speedup vs baseline: 1.2167x; 1.2167x over previous
//
#include <hip/hip_runtime.h>

// ChemResBlock: A=2048 atoms, D=64 depth, F=12 taps.
// out[a,o] = sum_{n,f} conn[a][n*12+f] * Gt[o][n*12+f] + bterm[a,o]
// conn viewed as (2048 x 24576) row-major is contiguous in exactly this K order.
// R3: conn pre-converted to bf16 once; GEMM uses global_load_lds(16B) staging,
// double-buffered LDS, XOR-swizzled chunks for conflict-free ds_read_b128.

#define A_N 2048
#define D_N 64
#define F_N 12
#define K_TOTAL (A_N * F_N)        // 24576
#define NSPLIT 48
#define KSEG (K_TOTAL / NSPLIT)    // 512
#define BK 64
#define NKB (KSEG / BK)            // 8

typedef short short8 __attribute__((ext_vector_type(8)));
typedef float f32x16 __attribute__((ext_vector_type(16)));

#define GLOAD16(ldsp, gp)                                                        \
  __builtin_amdgcn_global_load_lds(                                              \
      (const __attribute__((address_space(1))) void*)(gp),                       \
      (__attribute__((address_space(3))) void*)(ldsp), 16, 0, 0)

// pack two floats to bf16 pair with round-to-nearest-even
__device__ __forceinline__ unsigned pk_bf16(float a, float b) {
  unsigned ua = __float_as_uint(a);
  unsigned ub = __float_as_uint(b);
  ua += 0x7fffu + ((ua >> 16) & 1u);
  ub += 0x7fffu + ((ub >> 16) & 1u);
  return (ua >> 16) | (ub & 0xffff0000u);
}

// ---------------- one-time: conn fp32 -> bf16 (streaming) ----------------
__global__ void k_conv(const float* __restrict__ conn, uint4* __restrict__ connb) {
  size_t i = (size_t)blockIdx.x * 256 + threadIdx.x;  // 0 .. 6291455 (x8 floats)
  const float4* src = (const float4*)conn + i * 2;
  float4 c0 = src[0];
  float4 c1 = src[1];
  uint4 o;
  o.x = pk_bf16(c0.x, c0.y);
  o.y = pk_bf16(c0.z, c0.w);
  o.z = pk_bf16(c1.x, c1.y);
  o.w = pk_bf16(c1.z, c1.w);
  connb[i] = o;
}

// ---------------- prep: x (2048x64) -> xt (64x2048) ----------------
__global__ void k_transpose_x(const float* __restrict__ x, float* __restrict__ xt) {
  __shared__ float ld[64][65];
  int m0 = blockIdx.x * 64;
  int t = threadIdx.x;
  int r = t >> 2, cq = (t & 3) * 16;
  const float4* src = (const float4*)(x + (size_t)(m0 + r) * 64 + cq);
#pragma unroll
  for (int i = 0; i < 4; ++i) {
    float4 v = src[i];
    ld[r][cq + i * 4 + 0] = v.x;
    ld[r][cq + i * 4 + 1] = v.y;
    ld[r][cq + i * 4 + 2] = v.z;
    ld[r][cq + i * 4 + 3] = v.w;
  }
  __syncthreads();
  int c = t >> 2, ml0 = (t & 3) * 16;
  float4* dst = (float4*)(xt + (size_t)c * 2048 + m0 + ml0);
#pragma unroll
  for (int i = 0; i < 4; ++i) {
    float4 v;
    v.x = ld[ml0 + i * 4 + 0][c];
    v.y = ld[ml0 + i * 4 + 1][c];
    v.z = ld[ml0 + i * 4 + 2][c];
    v.w = ld[ml0 + i * 4 + 3][c];
    dst[i] = v;
  }
}

// ---------------- prep: bterm_t[o][a] for both filter sets ----------------
__global__ void k_bterm(const float* __restrict__ bond, const float* __restrict__ f0,
                        const float* __restrict__ f1, float* __restrict__ bt0,
                        float* __restrict__ bt1) {
  int a = blockIdx.x * 64 + (threadIdx.x & 63);
  int o = blockIdx.y * 4 + (threadIdx.x >> 6);
  float s0 = 0.f, s1 = 0.f;
#pragma unroll
  for (int f = 0; f < F_N; ++f) {
#pragma unroll
    for (int j = 0; j < 2; ++j) {
      float bv = bond[a * 24 + f * 2 + j];
      s0 += bv * f0[o * 792 + f * 66 + 64 + j];
      s1 += bv * f1[o * 792 + f * 66 + 64 + j];
    }
  }
  bt0[o * 2048 + a] = s0;
  bt1[o * 2048 + a] = s1;
}

// ---------------- per-layer: Gt[o][n*12+f] = sum_d vt[d][n]*filt[o][f][d] ----------------
__global__ void k_g(const float* __restrict__ vt, const float* __restrict__ filt,
                    unsigned* __restrict__ gt /* bf16 pairs */) {
  __shared__ float W[12][64];
  int o = blockIdx.y;
  int t = threadIdx.x;
  for (int i = t; i < 768; i += 256) W[i >> 6][i & 63] = filt[o * 792 + (i >> 6) * 66 + (i & 63)];
  __syncthreads();
  int n = blockIdx.x * 256 + t;
  float acc[12] = {0.f, 0.f, 0.f, 0.f, 0.f, 0.f, 0.f, 0.f, 0.f, 0.f, 0.f, 0.f};
#pragma unroll 4
  for (int d = 0; d < 64; ++d) {
    float v = vt[d * 2048 + n];
#pragma unroll
    for (int f = 0; f < F_N; ++f) acc[f] += v * W[f][d];
  }
  unsigned* dst = gt + ((size_t)o * K_TOTAL + n * 12) / 2;
#pragma unroll
  for (int i = 0; i < 6; ++i) dst[i] = pk_bf16(acc[2 * i], acc[2 * i + 1]);
}

// ---------------- per-layer: split-K GEMM with LDS staging ----------------
// Block: 128 atoms x 64 o, K-chunk 512. LDS tiles double-buffered:
//   conn tile 128 rows x 64 bf16 (16 KB), gt tile 64 x 64 (8 KB) -> 48 KB total.
// Chunk swizzle: 128-B row = 8 chunks of 16 B; chunk stored at c ^ (row&7).
// Staged via global_load_lds w=16 (source chunks permuted within the same
// 128-B line -> still fully coalesced). ds_read_b128 then conflict-free.
__launch_bounds__(256, 3)
__global__ void k_big(const unsigned short* __restrict__ connb,
                      const unsigned short* __restrict__ gt, float* __restrict__ part) {
  __shared__ __align__(16) unsigned short smem[24576];  // 48 KB
  int t = threadIdx.x, lane = t & 63, w = t >> 6;
  int m0 = blockIdx.x * 128;
  int k0 = blockIdx.y * KSEG;

  int rl = lane >> 3;              // 0..7: row within 8-row group
  int cs = (lane & 7) ^ rl;        // swizzled source chunk (16B units)

  // staging source pointers (advance by 64 bf16 per K-block)
  const unsigned short* cG[4];
  unsigned short* cL[4];
#pragma unroll
  for (int j = 0; j < 4; ++j) {
    int r = w * 32 + j * 8 + rl;   // conn row 0..127
    cG[j] = connb + (size_t)(m0 + r) * K_TOTAL + k0 + cs * 8;
    cL[j] = smem + (w * 32 + j * 8) * 64;
  }
  const unsigned short* gG[2];
  unsigned short* gL[2];
#pragma unroll
  for (int j = 0; j < 2; ++j) {
    int r = w * 16 + j * 8 + rl;   // gt row 0..63
    gG[j] = gt + (size_t)r * K_TOTAL + k0 + cs * 8;
    gL[j] = smem + 16384 + (w * 16 + j * 8) * 64;
  }

  f32x16 acc0, acc1;
#pragma unroll
  for (int i = 0; i < 16; ++i) { acc0[i] = 0.f; acc1[i] = 0.f; }

  int oh = w >> 1, ah = w & 1;
  int orow = oh * 32 + (lane & 31);
  int arow = ah * 64 + (lane & 31);
  int sw = lane & 7;
  int khalf = lane >> 5;

  // stage K-block 0 into buffer 0
#pragma unroll
  for (int j = 0; j < 4; ++j) GLOAD16(cL[j], cG[j]);
#pragma unroll
  for (int j = 0; j < 2; ++j) GLOAD16(gL[j], gG[j]);

  for (int kb = 0; kb < NKB; ++kb) {
    __syncthreads();  // drains vmcnt: buffer (kb&1) ready
    if (kb + 1 < NKB) {
      int ko = (kb + 1) * 64;
      int b = (kb + 1) & 1;
#pragma unroll
      for (int j = 0; j < 4; ++j) GLOAD16(cL[j] + b * 8192, cG[j] + ko);
#pragma unroll
      for (int j = 0; j < 2; ++j) GLOAD16(gL[j] + b * 4096, gG[j] + ko);
    }
    const unsigned short* cb = smem + (kb & 1) * 8192;
    const unsigned short* gb = smem + 16384 + (kb & 1) * 4096;
#pragma unroll
    for (int kk = 0; kk < 4; ++kk) {
      int c = kk * 2 + khalf;
      int coff = ((c ^ sw) << 3);
      short8 af = *(const short8*)(gb + orow * 64 + coff);
      short8 b0 = *(const short8*)(cb + arow * 64 + coff);
      short8 b1 = *(const short8*)(cb + (arow + 32) * 64 + coff);
      acc0 = __builtin_amdgcn_mfma_f32_32x32x16_bf16(af, b0, acc0, 0, 0, 0);
      acc1 = __builtin_amdgcn_mfma_f32_32x32x16_bf16(af, b1, acc1, 0, 0, 0);
    }
  }

  // D layout (32x32x16): col(atom) = lane&31, row(o) = (reg&3) + 8*(reg>>2) + 4*(lane>>5)
  float* pp = part + (size_t)blockIdx.y * (64 * 2048);
  int a0 = m0 + ah * 64 + (lane & 31);
  int ob = oh * 32 + 4 * khalf;
#pragma unroll
  for (int rg = 0; rg < 16; ++rg) {
    int o = ob + (rg & 3) + 8 * (rg >> 2);
    pp[o * 2048 + a0] = acc0[rg];
    pp[o * 2048 + a0 + 32] = acc1[rg];
  }
}

// ---------------- per-layer epilogue: sum partials + bterm (+x) + relu ----------------
__global__ void k_reduce(const float* __restrict__ part, const float* __restrict__ bt,
                         const float* __restrict__ xt, float* __restrict__ curt,
                         float* __restrict__ outp, int residual, int final_layer) {
  int idx = blockIdx.x * 256 + threadIdx.x;  // 0 .. 64*2048-1, layout [o][m]
  float s = bt[idx];
#pragma unroll
  for (int sI = 0; sI < NSPLIT; ++sI) s += part[(size_t)sI * (64 * 2048) + idx];
  if (residual) s += xt[idx];
  s = fmaxf(s, 0.f);
  curt[idx] = s;
  if (final_layer) {
    int o = idx >> 11, m = idx & 2047;
    outp[m * 64 + o] = s;
  }
}

extern "C" void kernel_launch(void* const* d_in, const int* in_sizes, int n_in,
                              void* d_out, int out_size, void* d_ws, size_t ws_size,
                              hipStream_t stream) {
  const float* x    = (const float*)d_in[0];  // (2048, 64)
  const float* conn = (const float*)d_in[1];  // (2048, 2048, 12)
  const float* bond = (const float*)d_in[2];  // (2048, 12, 2)
  const float* f0   = (const float*)d_in[3];  // (64, 12, 66)
  const float* f1   = (const float*)d_in[4];
  float* out = (float*)d_out;                 // (2048, 64)

  char* ws = (char*)d_ws;
  float* xt   = (float*)(ws + 0);              // 64x2048 fp32            512 KB
  float* curt = (float*)(ws + 524288);         // 64x2048 fp32            512 KB
  float* bt0  = (float*)(ws + 1048576);        // 64x2048 fp32            512 KB
  float* bt1  = (float*)(ws + 1572864);        // 64x2048 fp32            512 KB
  unsigned short* gt = (unsigned short*)(ws + 2097152);     // 64x24576 bf16  3 MB
  float* part = (float*)(ws + 5242880);        // 48 x 64x2048 fp32       24 MB
  unsigned short* connb = (unsigned short*)(ws + 33554432); // 2048x24576 bf16 96 MB
  // total ~130 MB of d_ws used

  k_conv<<<24576, 256, 0, stream>>>(conn, (uint4*)connb);
  k_transpose_x<<<32, 256, 0, stream>>>(x, xt);
  k_bterm<<<dim3(32, 16), 256, 0, stream>>>(bond, f0, f1, bt0, bt1);

  for (int layer = 0; layer < 4; ++layer) {
    const float* filt = (layer < 2) ? f0 : f1;
    const float* bt   = (layer < 2) ? bt0 : bt1;
    const float* vin  = (layer == 0) ? xt : curt;
    k_g<<<dim3(8, 64), 256, 0, stream>>>(vin, filt, (unsigned*)gt);
    k_big<<<dim3(16, NSPLIT), 256, 0, stream>>>(connb, gt, part);
    k_reduce<<<512, 256, 0, stream>>>(part, bt, xt, curt, out, layer & 1, layer == 3);
  }
}